// Round 1
// baseline (2076.068 us; speedup 1.0000x reference)
//
#include <hip/hip_runtime.h>

#define NRELS 8

// ---------------- counting / bucketing ----------------

__global__ __launch_bounds__(256) void count_kernel(
    const int* __restrict__ dstp, const int* __restrict__ et, int E,
    float* __restrict__ deg, int* __restrict__ cnt) {
  __shared__ int lcnt[NRELS];
  if (threadIdx.x < NRELS) lcnt[threadIdx.x] = 0;
  __syncthreads();
  int i = blockIdx.x * blockDim.x + threadIdx.x;
  if (i < E) {
    int t = et[i];
    atomicAdd(&deg[(size_t)dstp[i] * NRELS + t], 1.0f);
    atomicAdd(&lcnt[t], 1);
  }
  __syncthreads();
  if (threadIdx.x < NRELS && lcnt[threadIdx.x])
    atomicAdd(&cnt[threadIdx.x], lcnt[threadIdx.x]);
}

__global__ void scan_kernel(const int* __restrict__ cnt,
                            int* __restrict__ offsets, int* __restrict__ cursor) {
  int acc = 0;
  for (int r = 0; r < NRELS; r++) { offsets[r] = acc; cursor[r] = acc; acc += cnt[r]; }
  offsets[NRELS] = acc;
}

__global__ __launch_bounds__(256) void bucket_kernel(
    const int* __restrict__ et, int E, int* __restrict__ cursor, int* __restrict__ eord) {
  int i = blockIdx.x * blockDim.x + threadIdx.x;
  int lane = threadIdx.x & 63;
  int t = (i < E) ? et[i] : -1;
#pragma unroll
  for (int r = 0; r < NRELS; r++) {
    unsigned long long mask = __ballot(t == r);
    if (mask == 0ULL) continue;
    int leader = __ffsll((unsigned long long)mask) - 1;
    int base = 0;
    if (lane == leader) base = atomicAdd(&cursor[r], __popcll(mask));
    base = __shfl(base, leader);
    if (t == r) {
      int rank = __popcll(mask & ((1ULL << lane) - 1ULL));
      eord[base + rank] = i;
    }
  }
}

// ---------------- GEMM: C[N,BN] = act(A[N,128]) @ B[128,BN] (+bias) ----------------

template <int BN, bool RELU_A>
__global__ __launch_bounds__(256) void gemm_k128(
    const float* __restrict__ A, const float* __restrict__ B,
    const float* __restrict__ bias, float* __restrict__ C, int N) {
  constexpr int BM = 64;
  constexpr int BK = 32;
  constexpr int TM = 4;
  constexpr int TN = BN / 16;  // 8 (BN=128) or 4 (BN=64)

  __shared__ float As[BM][BK + 1];
  __shared__ float Bs[BK][BN];

  const int tid = threadIdx.x;
  const int tx = tid & 15;   // col group
  const int ty = tid >> 4;   // row group
  const int block_row = blockIdx.x * BM;

  float acc[TM][TN];
#pragma unroll
  for (int i = 0; i < TM; i++)
#pragma unroll
    for (int j = 0; j < TN; j++) acc[i][j] = 0.f;

  for (int kb = 0; kb < 128; kb += BK) {
    // A tile: 64x32 floats = 512 float4, 2 per thread
#pragma unroll
    for (int t = 0; t < 2; t++) {
      int idx = tid + t * 256;
      int row = idx >> 3;
      int c4 = (idx & 7) * 4;
      int grow = block_row + row;
      int srow = grow < N ? grow : (N - 1);
      float4 v = *(const float4*)(A + (size_t)srow * 128 + kb + c4);
      if (RELU_A) {
        v.x = fmaxf(v.x, 0.f); v.y = fmaxf(v.y, 0.f);
        v.z = fmaxf(v.z, 0.f); v.w = fmaxf(v.w, 0.f);
      }
      As[row][c4 + 0] = v.x; As[row][c4 + 1] = v.y;
      As[row][c4 + 2] = v.z; As[row][c4 + 3] = v.w;
    }
    // B tile: 32xBN floats
    constexpr int BF4 = (BK * BN) / 4 / 256;
#pragma unroll
    for (int t = 0; t < BF4; t++) {
      int idx = tid + t * 256;
      int row = idx / (BN / 4);
      int c4 = (idx % (BN / 4)) * 4;
      *(float4*)(&Bs[row][c4]) = *(const float4*)(B + (size_t)(kb + row) * BN + c4);
    }
    __syncthreads();

#pragma unroll
    for (int kk = 0; kk < BK; kk++) {
      float a[TM];
#pragma unroll
      for (int i = 0; i < TM; i++) a[i] = As[ty * TM + i][kk];
      float4 bv[TN / 4];
#pragma unroll
      for (int q = 0; q < TN / 4; q++)
        bv[q] = *(const float4*)(&Bs[kk][tx * TN + 4 * q]);
      const float* b = (const float*)bv;
#pragma unroll
      for (int i = 0; i < TM; i++)
#pragma unroll
        for (int j = 0; j < TN; j++) acc[i][j] += a[i] * b[j];
    }
    __syncthreads();
  }

#pragma unroll
  for (int i = 0; i < TM; i++) {
    int grow = block_row + ty * TM + i;
    if (grow < N) {
#pragma unroll
      for (int j = 0; j < TN; j += 4) {
        int col = tx * TN + j;
        float4 v = {acc[i][j], acc[i][j + 1], acc[i][j + 2], acc[i][j + 3]};
        if (bias) {
          v.x += bias[col]; v.y += bias[col + 1];
          v.z += bias[col + 2]; v.w += bias[col + 3];
        }
        *(float4*)(C + (size_t)grow * BN + col) = v;
      }
    }
  }
}

// ---------------- scatter: out[dst] += norm * xs[src] over one relation ----------------

template <int COLS>
__global__ __launch_bounds__(256) void scatter_rel(
    const float* __restrict__ xs, float* __restrict__ outp,
    const float* __restrict__ deg, const int* __restrict__ eord,
    const int* __restrict__ src, const int* __restrict__ dstp,
    const int* __restrict__ offsets, int r) {
  int begin = offsets[r], end = offsets[r + 1];
  int lane = threadIdx.x & 63;
  int wave = (int)((blockIdx.x * blockDim.x + threadIdx.x) >> 6);
  int nw = (int)((gridDim.x * blockDim.x) >> 6);
  for (int i = begin + wave; i < end; i += nw) {
    int e = eord[i];
    int s = src[e], d = dstp[e];
    float norm = 1.0f / fmaxf(deg[(size_t)d * NRELS + r], 1.0f);
    if (COLS == 128) {
      float2 v = *(const float2*)(xs + (size_t)s * 128 + lane * 2);
      atomicAdd(outp + (size_t)d * 128 + lane * 2, v.x * norm);
      atomicAdd(outp + (size_t)d * 128 + lane * 2 + 1, v.y * norm);
    } else {
      float v = xs[(size_t)s * 64 + lane];
      atomicAdd(outp + (size_t)d * 64 + lane, v * norm);
    }
  }
}

// ---------------- relu ----------------

__global__ __launch_bounds__(256) void relu_kernel(float* __restrict__ p, int n4) {
  int i = blockIdx.x * blockDim.x + threadIdx.x;
  if (i < n4) {
    float4 v = ((float4*)p)[i];
    v.x = fmaxf(v.x, 0.f); v.y = fmaxf(v.y, 0.f);
    v.z = fmaxf(v.z, 0.f); v.w = fmaxf(v.w, 0.f);
    ((float4*)p)[i] = v;
  }
}

// ---------------- launch ----------------

extern "C" void kernel_launch(void* const* d_in, const int* in_sizes, int n_in,
                              void* d_out, int out_size, void* d_ws, size_t ws_size,
                              hipStream_t stream) {
  const float* x     = (const float*)d_in[0];
  const int*   eidx  = (const int*)d_in[1];
  const int*   et    = (const int*)d_in[2];
  const float* W1    = (const float*)d_in[3];
  const float* root1 = (const float*)d_in[4];
  const float* b1    = (const float*)d_in[5];
  const float* W2    = (const float*)d_in[6];
  const float* root2 = (const float*)d_in[7];
  const float* b2    = (const float*)d_in[8];
  float* out = (float*)d_out;

  const int IN = 128, HD = 128, OD = 64;
  const int N = in_sizes[0] / IN;
  const int E = in_sizes[2];
  const int* src = eidx;
  const int* dst = eidx + E;

  auto align = [](size_t v) { return (v + 255) & ~(size_t)255; };
  char* base = (char*)d_ws;
  size_t o = 0;
  float* deg = (float*)(base + o);
  o = align(o + (size_t)N * NRELS * 4);
  int* cnt = (int*)(base + o);
  int* offsets = cnt + 8;
  int* cursor = offsets + 9;
  size_t meta_end = o + 25 * 4;
  o = align(meta_end);
  int* eord = (int*)(base + o);
  o = align(o + (size_t)E * 4);
  float* h = (float*)(base + o);
  o = align(o + (size_t)N * HD * 4);
  float* xs = (float*)(base + o);

  hipMemsetAsync(d_ws, 0, meta_end, stream);

  const int tb = 256;
  count_kernel<<<(E + tb - 1) / tb, tb, 0, stream>>>(dst, et, E, deg, cnt);
  scan_kernel<<<1, 1, 0, stream>>>(cnt, offsets, cursor);
  bucket_kernel<<<(E + tb - 1) / tb, tb, 0, stream>>>(et, E, cursor, eord);

  const int gblocks = (N + 63) / 64;

  // ----- layer 1: h = x@root1 + b1 + sum_r scatter(x@W1_r) -----
  gemm_k128<128, false><<<gblocks, 256, 0, stream>>>(x, root1, b1, h, N);
  for (int r = 0; r < NRELS; r++) {
    gemm_k128<128, false><<<gblocks, 256, 0, stream>>>(
        x, W1 + (size_t)r * IN * HD, nullptr, xs, N);
    scatter_rel<128><<<1024, 256, 0, stream>>>(xs, h, deg, eord, src, dst, offsets, r);
  }
  relu_kernel<<<((N * HD / 4) + tb - 1) / tb, tb, 0, stream>>>(h, N * HD / 4);

  // ----- layer 2: out = relu(h)@root2 + b2 + sum_r scatter(relu(h)@W2_r) -----
  gemm_k128<64, false><<<gblocks, 256, 0, stream>>>(h, root2, b2, out, N);
  for (int r = 0; r < NRELS; r++) {
    gemm_k128<64, false><<<gblocks, 256, 0, stream>>>(
        h, W2 + (size_t)r * HD * OD, nullptr, xs, N);
    scatter_rel<64><<<1024, 256, 0, stream>>>(xs, out, deg, eord, src, dst, offsets, r);
  }
}

// Round 2
// 1684.990 us; speedup vs baseline: 1.2321x; 1.2321x over previous
//
#include <hip/hip_runtime.h>

#define NRELS 8

// ---------------- degree histogram ----------------

__global__ __launch_bounds__(256) void deg_kernel(
    const int* __restrict__ dstp, const int* __restrict__ et, int E,
    float* __restrict__ deg) {
  int i = blockIdx.x * blockDim.x + threadIdx.x;
  if (i < E) {
    atomicAdd(&deg[(size_t)dstp[i] * NRELS + et[i]], 1.0f);
  }
}

// ---------------- GEMM: C[N,BN] = act(A[N,128]) @ B[128,BN] (+bias) ----------------

template <int BN, bool RELU_A>
__global__ __launch_bounds__(256) void gemm_k128(
    const float* __restrict__ A, const float* __restrict__ B,
    const float* __restrict__ bias, float* __restrict__ C, int N) {
  constexpr int BM = 64;
  constexpr int BK = 32;
  constexpr int TM = 4;
  constexpr int TN = BN / 16;  // 8 (BN=128) or 4 (BN=64)

  __shared__ float As[BM][BK + 1];
  __shared__ float Bs[BK][BN];

  const int tid = threadIdx.x;
  const int tx = tid & 15;   // col group
  const int ty = tid >> 4;   // row group
  const int block_row = blockIdx.x * BM;

  float acc[TM][TN];
#pragma unroll
  for (int i = 0; i < TM; i++)
#pragma unroll
    for (int j = 0; j < TN; j++) acc[i][j] = 0.f;

  for (int kb = 0; kb < 128; kb += BK) {
    // A tile: 64x32 floats = 512 float4, 2 per thread
#pragma unroll
    for (int t = 0; t < 2; t++) {
      int idx = tid + t * 256;
      int row = idx >> 3;
      int c4 = (idx & 7) * 4;
      int grow = block_row + row;
      int srow = grow < N ? grow : (N - 1);
      float4 v = *(const float4*)(A + (size_t)srow * 128 + kb + c4);
      if (RELU_A) {
        v.x = fmaxf(v.x, 0.f); v.y = fmaxf(v.y, 0.f);
        v.z = fmaxf(v.z, 0.f); v.w = fmaxf(v.w, 0.f);
      }
      As[row][c4 + 0] = v.x; As[row][c4 + 1] = v.y;
      As[row][c4 + 2] = v.z; As[row][c4 + 3] = v.w;
    }
    // B tile: 32xBN floats
    constexpr int BF4 = (BK * BN) / 4 / 256;
#pragma unroll
    for (int t = 0; t < BF4; t++) {
      int idx = tid + t * 256;
      int row = idx / (BN / 4);
      int c4 = (idx % (BN / 4)) * 4;
      *(float4*)(&Bs[row][c4]) = *(const float4*)(B + (size_t)(kb + row) * BN + c4);
    }
    __syncthreads();

#pragma unroll
    for (int kk = 0; kk < BK; kk++) {
      float a[TM];
#pragma unroll
      for (int i = 0; i < TM; i++) a[i] = As[ty * TM + i][kk];
      float4 bv[TN / 4];
#pragma unroll
      for (int q = 0; q < TN / 4; q++)
        bv[q] = *(const float4*)(&Bs[kk][tx * TN + 4 * q]);
      const float* b = (const float*)bv;
#pragma unroll
      for (int i = 0; i < TM; i++)
#pragma unroll
        for (int j = 0; j < TN; j++) acc[i][j] += a[i] * b[j];
    }
    __syncthreads();
  }

#pragma unroll
  for (int i = 0; i < TM; i++) {
    int grow = block_row + ty * TM + i;
    if (grow < N) {
#pragma unroll
      for (int j = 0; j < TN; j += 4) {
        int col = tx * TN + j;
        float4 v = {acc[i][j], acc[i][j + 1], acc[i][j + 2], acc[i][j + 3]};
        if (bias) {
          v.x += bias[col]; v.y += bias[col + 1];
          v.z += bias[col + 2]; v.w += bias[col + 3];
        }
        *(float4*)(C + (size_t)grow * BN + col) = v;
      }
    }
  }
}

// ---------------- scatter: out[dst] += norm * xs[src] over edges with et==r ----------------

template <int COLS>
__global__ __launch_bounds__(256) void scatter_rel(
    const float* __restrict__ xs, float* __restrict__ outp,
    const float* __restrict__ deg,
    const int* __restrict__ src, const int* __restrict__ dstp,
    const int* __restrict__ et, int E, int r) {
  int lane = threadIdx.x & 63;
  int wave = (int)((blockIdx.x * blockDim.x + threadIdx.x) >> 6);
  int nw = (int)((gridDim.x * blockDim.x) >> 6);
  for (int i = wave; i < E; i += nw) {
    if (et[i] != r) continue;  // wave-uniform filter
    int s = src[i], d = dstp[i];
    float norm = 1.0f / fmaxf(deg[(size_t)d * NRELS + r], 1.0f);
    if (COLS == 128) {
      float2 v = *(const float2*)(xs + (size_t)s * 128 + lane * 2);
      atomicAdd(outp + (size_t)d * 128 + lane * 2, v.x * norm);
      atomicAdd(outp + (size_t)d * 128 + lane * 2 + 1, v.y * norm);
    } else {
      float v = xs[(size_t)s * 64 + lane];
      atomicAdd(outp + (size_t)d * 64 + lane, v * norm);
    }
  }
}

// ---------------- launch ----------------

extern "C" void kernel_launch(void* const* d_in, const int* in_sizes, int n_in,
                              void* d_out, int out_size, void* d_ws, size_t ws_size,
                              hipStream_t stream) {
  const float* x     = (const float*)d_in[0];
  const int*   eidx  = (const int*)d_in[1];
  const int*   et    = (const int*)d_in[2];
  const float* W1    = (const float*)d_in[3];
  const float* root1 = (const float*)d_in[4];
  const float* b1    = (const float*)d_in[5];
  const float* W2    = (const float*)d_in[6];
  const float* root2 = (const float*)d_in[7];
  const float* b2    = (const float*)d_in[8];
  float* out = (float*)d_out;

  const int IN = 128, HD = 128, OD = 64;
  const int N = in_sizes[0] / IN;
  const int E = in_sizes[2];
  const int* src = eidx;
  const int* dst = eidx + E;

  auto align = [](size_t v) { return (v + 255) & ~(size_t)255; };
  char* base = (char*)d_ws;
  size_t o = 0;
  float* deg = (float*)(base + o);
  size_t deg_bytes = (size_t)N * NRELS * 4;
  o = align(o + deg_bytes);
  float* h = (float*)(base + o);
  o = align(o + (size_t)N * HD * 4);
  float* xs = (float*)(base + o);

  hipMemsetAsync(deg, 0, deg_bytes, stream);

  const int tb = 256;
  deg_kernel<<<(E + tb - 1) / tb, tb, 0, stream>>>(dst, et, E, deg);

  const int gblocks = (N + 63) / 64;

  // ----- layer 1: h = x@root1 + b1 + sum_r scatter(x@W1_r) -----
  gemm_k128<128, false><<<gblocks, 256, 0, stream>>>(x, root1, b1, h, N);
  for (int r = 0; r < NRELS; r++) {
    gemm_k128<128, false><<<gblocks, 256, 0, stream>>>(
        x, W1 + (size_t)r * IN * HD, nullptr, xs, N);
    scatter_rel<128><<<1024, 256, 0, stream>>>(xs, h, deg, src, dst, et, E, r);
  }

  // ----- layer 2: out = relu(h)@root2 + b2 + sum_r scatter(relu(h)@W2_r) -----
  // ReLU fused into the GEMM A-load (h itself stays pre-activation).
  gemm_k128<64, true><<<gblocks, 256, 0, stream>>>(h, root2, b2, out, N);
  for (int r = 0; r < NRELS; r++) {
    gemm_k128<64, true><<<gblocks, 256, 0, stream>>>(
        h, W2 + (size_t)r * HD * OD, nullptr, xs, N);
    scatter_rel<64><<<1024, 256, 0, stream>>>(xs, out, deg, src, dst, et, E, r);
  }
}

// Round 3
// 765.707 us; speedup vs baseline: 2.7113x; 2.2006x over previous
//
#include <hip/hip_runtime.h>

#define NRELS 8

// ---------------- degree histogram (per (dst,rel)) + per-dst count ----------------

__global__ __launch_bounds__(256) void deg_kernel(
    const int* __restrict__ dstp, const int* __restrict__ et, int E,
    float* __restrict__ deg, int* __restrict__ cnt) {
  int i = blockIdx.x * blockDim.x + threadIdx.x;
  if (i < E) {
    int d = dstp[i];
    atomicAdd(&deg[(size_t)d * NRELS + et[i]], 1.0f);
    atomicAdd(&cnt[d], 1);
  }
}

// ---------------- single-block exclusive scan: cnt[N] -> row_off[N+1], cursor ----------------

__global__ __launch_bounds__(1024) void scan_kernel(
    const int* __restrict__ cnt, int N, int* __restrict__ row_off,
    int* __restrict__ cursor) {
  __shared__ int s[1024];
  int t = threadIdx.x;
  int C = (N + 1023) / 1024;
  int b0 = t * C;
  int b1 = min(N, b0 + C);
  int sum = 0;
  for (int i = b0; i < b1; i++) sum += cnt[i];
  s[t] = sum;
  __syncthreads();
  for (int off = 1; off < 1024; off <<= 1) {
    int v = (t >= off) ? s[t - off] : 0;
    __syncthreads();
    s[t] += v;
    __syncthreads();
  }
  int base = (t == 0) ? 0 : s[t - 1];
  for (int i = b0; i < b1; i++) {
    row_off[i] = base;
    cursor[i] = base;
    base += cnt[i];
  }
  if (t == 1023) row_off[N] = s[1023];
}

// ---------------- bucket edges by dst; pack (src | et<<20) ----------------

__global__ __launch_bounds__(256) void bucket_kernel(
    const int* __restrict__ src, const int* __restrict__ dstp,
    const int* __restrict__ et, int E, int* __restrict__ cursor,
    int* __restrict__ epack) {
  int i = blockIdx.x * blockDim.x + threadIdx.x;
  if (i < E) {
    int pos = atomicAdd(&cursor[dstp[i]], 1);
    epack[pos] = src[i] | (et[i] << 20);
  }
}

// ---------------- aggregate ALL 8 relations in one pass: agg[node][r][128] ----------------
// one wave per dst node; zero atomics

template <bool RELU_SRC>
__global__ __launch_bounds__(256) void agg_all_kernel(
    const float* __restrict__ feat, const float* __restrict__ deg,
    const int* __restrict__ row_off, const int* __restrict__ epack,
    float* __restrict__ agg, int N) {
  int wid = (int)((blockIdx.x * blockDim.x + threadIdx.x) >> 6);
  if (wid >= N) return;
  int lane = threadIdx.x & 63;
  float acc[NRELS][2];
#pragma unroll
  for (int r = 0; r < NRELS; r++) { acc[r][0] = 0.f; acc[r][1] = 0.f; }
  int b = row_off[wid], e = row_off[wid + 1];
  for (int i = b; i < e; i++) {
    int p = epack[i];
    int s = p & 0xFFFFF;
    int t = p >> 20;
    float2 v = *(const float2*)(feat + (size_t)s * 128 + lane * 2);
    if (RELU_SRC) { v.x = fmaxf(v.x, 0.f); v.y = fmaxf(v.y, 0.f); }
#pragma unroll
    for (int r = 0; r < NRELS; r++) {
      if (t == r) { acc[r][0] += v.x; acc[r][1] += v.y; }
    }
  }
#pragma unroll
  for (int r = 0; r < NRELS; r++) {
    float nrm = 1.0f / fmaxf(deg[(size_t)wid * NRELS + r], 1.0f);
    float2 o = {acc[r][0] * nrm, acc[r][1] * nrm};
    *(float2*)(agg + ((size_t)wid * NRELS + r) * 128 + lane * 2) = o;
  }
}

// ---------------- aggregate one relation: aggr[node][128] (fallback path) ----------------

template <bool RELU_SRC>
__global__ __launch_bounds__(256) void agg_one_kernel(
    const float* __restrict__ feat, const float* __restrict__ deg,
    const int* __restrict__ row_off, const int* __restrict__ epack,
    float* __restrict__ aggr, int N, int rsel) {
  int wid = (int)((blockIdx.x * blockDim.x + threadIdx.x) >> 6);
  if (wid >= N) return;
  int lane = threadIdx.x & 63;
  float a0 = 0.f, a1 = 0.f;
  int b = row_off[wid], e = row_off[wid + 1];
  for (int i = b; i < e; i++) {
    int p = epack[i];
    int s = p & 0xFFFFF;
    int t = p >> 20;
    if (t != rsel) continue;
    float2 v = *(const float2*)(feat + (size_t)s * 128 + lane * 2);
    if (RELU_SRC) { v.x = fmaxf(v.x, 0.f); v.y = fmaxf(v.y, 0.f); }
    a0 += v.x; a1 += v.y;
  }
  float nrm = 1.0f / fmaxf(deg[(size_t)wid * NRELS + rsel], 1.0f);
  float2 o = {a0 * nrm, a1 * nrm};
  *(float2*)(aggr + (size_t)wid * 128 + lane * 2) = o;
}

// ---------------- big-K GEMM: C = A1[N,1024]@B1[1024,BN] + act(A2[N,128])@B2[128,BN] + bias ----

template <int BN, bool RELU_A2>
__global__ __launch_bounds__(256) void gemm_bigk(
    const float* __restrict__ A1, const float* __restrict__ B1,
    const float* __restrict__ A2, const float* __restrict__ B2,
    const float* __restrict__ bias, float* __restrict__ C, int N) {
  constexpr int BM = 64;
  constexpr int BK = 32;
  constexpr int TM = 4;
  constexpr int TN = BN / 16;
  constexpr int K1 = 1024, K2 = 128;

  __shared__ float As[BM][BK + 1];
  __shared__ float Bs[BK][BN];

  const int tid = threadIdx.x;
  const int tx = tid & 15;
  const int ty = tid >> 4;
  const int block_row = blockIdx.x * BM;

  float acc[TM][TN];
#pragma unroll
  for (int i = 0; i < TM; i++)
#pragma unroll
    for (int j = 0; j < TN; j++) acc[i][j] = 0.f;

  for (int kb = 0; kb < K1 + K2; kb += BK) {
    const bool first = kb < K1;
#pragma unroll
    for (int t = 0; t < 2; t++) {
      int idx = tid + t * 256;
      int row = idx >> 3;
      int c4 = (idx & 7) * 4;
      int grow = block_row + row;
      int srow = grow < N ? grow : (N - 1);
      const float* ap = first ? (A1 + (size_t)srow * K1 + kb + c4)
                              : (A2 + (size_t)srow * K2 + (kb - K1) + c4);
      float4 v = *(const float4*)ap;
      if (!first && RELU_A2) {
        v.x = fmaxf(v.x, 0.f); v.y = fmaxf(v.y, 0.f);
        v.z = fmaxf(v.z, 0.f); v.w = fmaxf(v.w, 0.f);
      }
      As[row][c4 + 0] = v.x; As[row][c4 + 1] = v.y;
      As[row][c4 + 2] = v.z; As[row][c4 + 3] = v.w;
    }
    constexpr int BF4 = (BK * BN) / 4 / 256;
#pragma unroll
    for (int t = 0; t < BF4; t++) {
      int idx = tid + t * 256;
      int row = idx / (BN / 4);
      int c4 = (idx % (BN / 4)) * 4;
      const float* bp = first ? (B1 + (size_t)(kb + row) * BN + c4)
                              : (B2 + (size_t)(kb - K1 + row) * BN + c4);
      *(float4*)(&Bs[row][c4]) = *(const float4*)bp;
    }
    __syncthreads();

#pragma unroll
    for (int kk = 0; kk < BK; kk++) {
      float a[TM];
#pragma unroll
      for (int i = 0; i < TM; i++) a[i] = As[ty * TM + i][kk];
      float4 bv[TN / 4];
#pragma unroll
      for (int q = 0; q < TN / 4; q++)
        bv[q] = *(const float4*)(&Bs[kk][tx * TN + 4 * q]);
      const float* bb = (const float*)bv;
#pragma unroll
      for (int i = 0; i < TM; i++)
#pragma unroll
        for (int j = 0; j < TN; j++) acc[i][j] += a[i] * bb[j];
    }
    __syncthreads();
  }

#pragma unroll
  for (int i = 0; i < TM; i++) {
    int grow = block_row + ty * TM + i;
    if (grow < N) {
#pragma unroll
      for (int j = 0; j < TN; j += 4) {
        int col = tx * TN + j;
        float4 v = {acc[i][j], acc[i][j + 1], acc[i][j + 2], acc[i][j + 3]};
        v.x += bias[col]; v.y += bias[col + 1];
        v.z += bias[col + 2]; v.w += bias[col + 3];
        *(float4*)(C + (size_t)grow * BN + col) = v;
      }
    }
  }
}

// ---------------- K=128 GEMM (fallback path): C (+)= act(A)@B (+bias) ----------------

template <int BN, bool RELU_A, bool ACCUM>
__global__ __launch_bounds__(256) void gemm_k128(
    const float* __restrict__ A, const float* __restrict__ B,
    const float* __restrict__ bias, float* __restrict__ C, int N) {
  constexpr int BM = 64;
  constexpr int BK = 32;
  constexpr int TM = 4;
  constexpr int TN = BN / 16;

  __shared__ float As[BM][BK + 1];
  __shared__ float Bs[BK][BN];

  const int tid = threadIdx.x;
  const int tx = tid & 15;
  const int ty = tid >> 4;
  const int block_row = blockIdx.x * BM;

  float acc[TM][TN];
#pragma unroll
  for (int i = 0; i < TM; i++)
#pragma unroll
    for (int j = 0; j < TN; j++) acc[i][j] = 0.f;

  for (int kb = 0; kb < 128; kb += BK) {
#pragma unroll
    for (int t = 0; t < 2; t++) {
      int idx = tid + t * 256;
      int row = idx >> 3;
      int c4 = (idx & 7) * 4;
      int grow = block_row + row;
      int srow = grow < N ? grow : (N - 1);
      float4 v = *(const float4*)(A + (size_t)srow * 128 + kb + c4);
      if (RELU_A) {
        v.x = fmaxf(v.x, 0.f); v.y = fmaxf(v.y, 0.f);
        v.z = fmaxf(v.z, 0.f); v.w = fmaxf(v.w, 0.f);
      }
      As[row][c4 + 0] = v.x; As[row][c4 + 1] = v.y;
      As[row][c4 + 2] = v.z; As[row][c4 + 3] = v.w;
    }
    constexpr int BF4 = (BK * BN) / 4 / 256;
#pragma unroll
    for (int t = 0; t < BF4; t++) {
      int idx = tid + t * 256;
      int row = idx / (BN / 4);
      int c4 = (idx % (BN / 4)) * 4;
      *(float4*)(&Bs[row][c4]) = *(const float4*)(B + (size_t)(kb + row) * BN + c4);
    }
    __syncthreads();

#pragma unroll
    for (int kk = 0; kk < BK; kk++) {
      float a[TM];
#pragma unroll
      for (int i = 0; i < TM; i++) a[i] = As[ty * TM + i][kk];
      float4 bv[TN / 4];
#pragma unroll
      for (int q = 0; q < TN / 4; q++)
        bv[q] = *(const float4*)(&Bs[kk][tx * TN + 4 * q]);
      const float* bb = (const float*)bv;
#pragma unroll
      for (int i = 0; i < TM; i++)
#pragma unroll
        for (int j = 0; j < TN; j++) acc[i][j] += a[i] * bb[j];
    }
    __syncthreads();
  }

#pragma unroll
  for (int i = 0; i < TM; i++) {
    int grow = block_row + ty * TM + i;
    if (grow < N) {
#pragma unroll
      for (int j = 0; j < TN; j += 4) {
        int col = tx * TN + j;
        float4 v = {acc[i][j], acc[i][j + 1], acc[i][j + 2], acc[i][j + 3]};
        if (bias) {
          v.x += bias[col]; v.y += bias[col + 1];
          v.z += bias[col + 2]; v.w += bias[col + 3];
        }
        if (ACCUM) {
          float4 c0 = *(const float4*)(C + (size_t)grow * BN + col);
          v.x += c0.x; v.y += c0.y; v.z += c0.z; v.w += c0.w;
        }
        *(float4*)(C + (size_t)grow * BN + col) = v;
      }
    }
  }
}

// ---------------- launch ----------------

extern "C" void kernel_launch(void* const* d_in, const int* in_sizes, int n_in,
                              void* d_out, int out_size, void* d_ws, size_t ws_size,
                              hipStream_t stream) {
  const float* x     = (const float*)d_in[0];
  const int*   eidx  = (const int*)d_in[1];
  const int*   et    = (const int*)d_in[2];
  const float* W1    = (const float*)d_in[3];
  const float* root1 = (const float*)d_in[4];
  const float* b1    = (const float*)d_in[5];
  const float* W2    = (const float*)d_in[6];
  const float* root2 = (const float*)d_in[7];
  const float* b2    = (const float*)d_in[8];
  float* out = (float*)d_out;

  const int IN = 128, HD = 128, OD = 64;
  const int N = in_sizes[0] / IN;
  const int E = in_sizes[2];
  const int* src = eidx;
  const int* dst = eidx + E;

  auto align = [](size_t v) { return (v + 255) & ~(size_t)255; };
  char* base = (char*)d_ws;
  size_t o = 0;
  float* deg = (float*)(base + o);
  o = align(o + (size_t)N * NRELS * 4);
  int* cnt = (int*)(base + o);
  size_t zero_end = o + (size_t)N * 4;   // memset covers deg..cnt
  o = align(zero_end);
  int* row_off = (int*)(base + o);
  o = align(o + (size_t)(N + 1) * 4);
  int* cursor = (int*)(base + o);
  o = align(o + (size_t)N * 4);
  int* epack = (int*)(base + o);
  o = align(o + (size_t)E * 4);
  float* h = (float*)(base + o);
  o = align(o + (size_t)N * HD * 4);
  float* aggbuf = (float*)(base + o);   // A: [N][8][128]; B: [N][128]
  size_t needA = o + (size_t)N * NRELS * 128 * 4;
  size_t needB = o + (size_t)N * 128 * 4;
  const bool bigpath = (ws_size >= needA);
  (void)needB;

  hipMemsetAsync(deg, 0, zero_end, stream);

  const int tb = 256;
  deg_kernel<<<(E + tb - 1) / tb, tb, 0, stream>>>(dst, et, E, deg, cnt);
  scan_kernel<<<1, 1024, 0, stream>>>(cnt, N, row_off, cursor);
  bucket_kernel<<<(E + tb - 1) / tb, tb, 0, stream>>>(src, dst, et, E, cursor, epack);

  const int agrid = (N + 3) / 4;        // 4 waves per 256-thread block
  const int gblocks = (N + 63) / 64;

  if (bigpath) {
    // layer 1
    agg_all_kernel<false><<<agrid, 256, 0, stream>>>(x, deg, row_off, epack, aggbuf, N);
    gemm_bigk<128, false><<<gblocks, 256, 0, stream>>>(aggbuf, W1, x, root1, b1, h, N);
    // layer 2 (relu applied at gather / root-A load; h stays pre-activation)
    agg_all_kernel<true><<<agrid, 256, 0, stream>>>(h, deg, row_off, epack, aggbuf, N);
    gemm_bigk<64, true><<<gblocks, 256, 0, stream>>>(aggbuf, W2, h, root2, b2, out, N);
  } else {
    // layer 1
    gemm_k128<128, false, false><<<gblocks, 256, 0, stream>>>(x, root1, b1, h, N);
    for (int r = 0; r < NRELS; r++) {
      agg_one_kernel<false><<<agrid, 256, 0, stream>>>(x, deg, row_off, epack, aggbuf, N, r);
      gemm_k128<128, false, true><<<gblocks, 256, 0, stream>>>(
          aggbuf, W1 + (size_t)r * IN * HD, nullptr, h, N);
    }
    // layer 2
    gemm_k128<64, true, false><<<gblocks, 256, 0, stream>>>(h, root2, b2, out, N);
    for (int r = 0; r < NRELS; r++) {
      agg_one_kernel<true><<<agrid, 256, 0, stream>>>(h, deg, row_off, epack, aggbuf, N, r);
      gemm_k128<64, false, true><<<gblocks, 256, 0, stream>>>(
          aggbuf, W2 + (size_t)r * HD * OD, nullptr, out, N);
    }
  }
}

// Round 4
// 420.168 us; speedup vs baseline: 4.9410x; 1.8224x over previous
//
#include <hip/hip_runtime.h>

#define NRELS 8

typedef __attribute__((ext_vector_type(8))) short short8;
typedef __attribute__((ext_vector_type(4))) float f32x4;

__device__ __forceinline__ unsigned short f2bf(float f) {
  unsigned int u = __float_as_uint(f);
  u += 0x7FFFu + ((u >> 16) & 1u);
  return (unsigned short)(u >> 16);
}
__device__ __forceinline__ float bf2f(unsigned short h) {
  return __uint_as_float(((unsigned int)h) << 16);
}

__device__ __forceinline__ void gload_lds16(const void* g, void* l) {
  __builtin_amdgcn_global_load_lds(
      (const __attribute__((address_space(1))) unsigned int*)g,
      (__attribute__((address_space(3))) unsigned int*)l, 16, 0, 0);
}

// ---------------- degree histogram (per (dst,rel)) + per-dst count ----------------

__global__ __launch_bounds__(256) void deg_kernel(
    const int* __restrict__ dstp, const int* __restrict__ et, int E,
    float* __restrict__ deg, int* __restrict__ cnt) {
  int i = blockIdx.x * blockDim.x + threadIdx.x;
  if (i < E) {
    int d = dstp[i];
    atomicAdd(&deg[(size_t)d * NRELS + et[i]], 1.0f);
    atomicAdd(&cnt[d], 1);
  }
}

// ---------------- single-block exclusive scan ----------------

__global__ __launch_bounds__(1024) void scan_kernel(
    const int* __restrict__ cnt, int N, int* __restrict__ row_off,
    int* __restrict__ cursor) {
  __shared__ int s[1024];
  int t = threadIdx.x;
  int C = (N + 1023) / 1024;
  int b0 = t * C;
  int b1 = min(N, b0 + C);
  int sum = 0;
  for (int i = b0; i < b1; i++) sum += cnt[i];
  s[t] = sum;
  __syncthreads();
  for (int off = 1; off < 1024; off <<= 1) {
    int v = (t >= off) ? s[t - off] : 0;
    __syncthreads();
    s[t] += v;
    __syncthreads();
  }
  int base = (t == 0) ? 0 : s[t - 1];
  for (int i = b0; i < b1; i++) {
    row_off[i] = base;
    cursor[i] = base;
    base += cnt[i];
  }
  if (t == 1023) row_off[N] = s[1023];
}

// ---------------- bucket edges by dst; pack (src | et<<20) ----------------

__global__ __launch_bounds__(256) void bucket_kernel(
    const int* __restrict__ src, const int* __restrict__ dstp,
    const int* __restrict__ et, int E, int* __restrict__ cursor,
    int* __restrict__ epack) {
  int i = blockIdx.x * blockDim.x + threadIdx.x;
  if (i < E) {
    int pos = atomicAdd(&cursor[dstp[i]], 1);
    epack[pos] = src[i] | (et[i] << 20);
  }
}

// ---------------- fp32 -> bf16 feature conversion ----------------

__global__ __launch_bounds__(256) void cvt_x_kernel(
    const float* __restrict__ x, unsigned short* __restrict__ xb, int n4) {
  int i = blockIdx.x * blockDim.x + threadIdx.x;
  if (i < n4) {
    float4 v = ((const float4*)x)[i];
    ushort4 o;
    o.x = f2bf(v.x); o.y = f2bf(v.y); o.z = f2bf(v.z); o.w = f2bf(v.w);
    ((ushort4*)xb)[i] = o;
  }
}

// ---------------- weights -> bf16, transposed to [n][k] with k = [8*128 | 128] ------

__global__ __launch_bounds__(256) void cvt_w_kernel(
    const float* __restrict__ W1, const float* __restrict__ root1,
    const float* __restrict__ W2, const float* __restrict__ root2,
    unsigned short* __restrict__ Wt1, unsigned short* __restrict__ Wt2) {
  int idx = blockIdx.x * blockDim.x + threadIdx.x;
  const int T1 = 128 * 1152;
  const int T2 = 64 * 1152;
  if (idx < T1) {
    int n = idx / 1152, k = idx % 1152;
    float v = (k < 1024) ? W1[(size_t)k * 128 + n] : root1[(size_t)(k - 1024) * 128 + n];
    Wt1[idx] = f2bf(v);
  } else if (idx < T1 + T2) {
    int j = idx - T1;
    int n = j / 1152, k = j % 1152;
    float v = (k < 1024) ? W2[(size_t)k * 64 + n] : root2[(size_t)(k - 1024) * 64 + n];
    Wt2[j] = f2bf(v);
  }
}

// ---------------- aggregate all 8 relations + copy own row: Abig[node][1152] bf16 ----
// one wave per dst node; zero atomics; fp32 accumulation

__global__ __launch_bounds__(256) void agg_kernel(
    const unsigned short* __restrict__ feat,  // [N][128] bf16
    const float* __restrict__ deg,
    const int* __restrict__ row_off, const int* __restrict__ epack,
    unsigned short* __restrict__ Abig,        // [N][1152] bf16
    int N) {
  int wid = (int)((blockIdx.x * blockDim.x + threadIdx.x) >> 6);
  if (wid >= N) return;
  int lane = threadIdx.x & 63;
  float acc[NRELS][2];
#pragma unroll
  for (int r = 0; r < NRELS; r++) { acc[r][0] = 0.f; acc[r][1] = 0.f; }
  int b = row_off[wid], e = row_off[wid + 1];
  for (int i = b; i < e; i++) {
    int p = epack[i];
    int s = p & 0xFFFFF;
    int t = p >> 20;
    unsigned int pv = *(const unsigned int*)(feat + (size_t)s * 128 + lane * 2);
    float v0 = bf2f((unsigned short)(pv & 0xFFFF));
    float v1 = bf2f((unsigned short)(pv >> 16));
#pragma unroll
    for (int r = 0; r < NRELS; r++) {
      if (t == r) { acc[r][0] += v0; acc[r][1] += v1; }
    }
  }
  size_t arow = (size_t)wid * 1152;
#pragma unroll
  for (int r = 0; r < NRELS; r++) {
    float nrm = 1.0f / fmaxf(deg[(size_t)wid * NRELS + r], 1.0f);
    unsigned int o = (unsigned int)f2bf(acc[r][0] * nrm) |
                     ((unsigned int)f2bf(acc[r][1] * nrm) << 16);
    *(unsigned int*)(Abig + arow + r * 128 + lane * 2) = o;
  }
  unsigned int own = *(const unsigned int*)(feat + (size_t)wid * 128 + lane * 2);
  *(unsigned int*)(Abig + arow + 1024 + lane * 2) = own;
}

// ---------------- MFMA GEMM: C[N,BN] = A[N,1152] @ Bt[BN,1152]^T + bias ----------------
// BM=64 rows/block, 4 waves in 2x2; 16x16x32 bf16 MFMA; global_load_lds staging
// with XOR swizzle (byte ^= (row&7)<<4) applied on global source + ds_read.

template <int BN, bool RELU_BF16_OUT>
__global__ __launch_bounds__(256) void gemm_mfma(
    const unsigned short* __restrict__ A,   // [N][1152] bf16
    const unsigned short* __restrict__ Bt,  // [BN][1152] bf16
    const float* __restrict__ bias,         // [BN] fp32
    void* __restrict__ Cout, int N) {
  constexpr int K = 1152;
  constexpr int BM = 64;
  constexpr int FM = 2;
  constexpr int FN = BN / 32;  // 4 (BN=128) or 2 (BN=64)

  __shared__ unsigned short As[BM * 64];  // 8 KB,  row stride 128 B
  __shared__ unsigned short Bs[BN * 64];  // 16/8 KB

  const int tid = threadIdx.x;
  const int lane = tid & 63;
  const int wid = tid >> 6;
  const int wm = wid >> 1, wn = wid & 1;
  const int l15 = lane & 15, lhi = lane >> 4;
  const int bm0 = blockIdx.x * BM;

  f32x4 acc[FM][FN];
#pragma unroll
  for (int i = 0; i < FM; i++)
#pragma unroll
    for (int j = 0; j < FN; j++) acc[i][j] = (f32x4){0.f, 0.f, 0.f, 0.f};

  // fragment LDS byte addresses (fixed across K loop)
  int a_addr[2][FM], b_addr[2][FN];
#pragma unroll
  for (int fm = 0; fm < FM; fm++) {
    int row = wm * 32 + fm * 16 + l15;
#pragma unroll
    for (int ks = 0; ks < 2; ks++) {
      int colb = ks * 64 + lhi * 16;
      a_addr[ks][fm] = row * 128 + (colb ^ ((row & 7) << 4));
    }
  }
#pragma unroll
  for (int fn = 0; fn < FN; fn++) {
    int n = wn * (BN / 2) + fn * 16 + l15;
#pragma unroll
    for (int ks = 0; ks < 2; ks++) {
      int colb = ks * 64 + lhi * 16;
      b_addr[ks][fn] = n * 128 + (colb ^ ((n & 7) << 4));
    }
  }

  for (int kb = 0; kb < K; kb += 64) {
    if (kb) __syncthreads();
    // stage A tile (BM x 64 bf16): BM/32 iters of 16B per thread
#pragma unroll
    for (int itr = 0; itr < BM / 32; itr++) {
      int o = itr * 4096 + wid * 1024 + lane * 16;
      int row = o >> 7;
      int scol = ((o & 127) ^ ((row & 7) << 4)) >> 1;
      int gr = bm0 + row;
      gr = gr < N ? gr : N - 1;
      gload_lds16(A + (size_t)gr * K + kb + scol,
                  (char*)As + itr * 4096 + wid * 1024);
    }
    // stage B tile (BN x 64 bf16)
#pragma unroll
    for (int itr = 0; itr < BN / 32; itr++) {
      int o = itr * 4096 + wid * 1024 + lane * 16;
      int n = o >> 7;
      int scol = ((o & 127) ^ ((n & 7) << 4)) >> 1;
      gload_lds16(Bt + (size_t)n * K + kb + scol,
                  (char*)Bs + itr * 4096 + wid * 1024);
    }
    asm volatile("s_waitcnt vmcnt(0)" ::: "memory");
    __syncthreads();

#pragma unroll
    for (int ks = 0; ks < 2; ks++) {
      short8 af[FM], bf[FN];
#pragma unroll
      for (int fm = 0; fm < FM; fm++)
        af[fm] = *(const short8*)((const char*)As + a_addr[ks][fm]);
#pragma unroll
      for (int fn = 0; fn < FN; fn++)
        bf[fn] = *(const short8*)((const char*)Bs + b_addr[ks][fn]);
#pragma unroll
      for (int fm = 0; fm < FM; fm++)
#pragma unroll
        for (int fn = 0; fn < FN; fn++)
          acc[fm][fn] = __builtin_amdgcn_mfma_f32_16x16x32_bf16(
              af[fm], bf[fn], acc[fm][fn], 0, 0, 0);
    }
  }

  // epilogue: C row = bm0 + wm*32 + fm*16 + lhi*4 + i ; col = wn*(BN/2) + fn*16 + l15
#pragma unroll
  for (int fm = 0; fm < FM; fm++) {
#pragma unroll
    for (int fn = 0; fn < FN; fn++) {
      int col = wn * (BN / 2) + fn * 16 + l15;
      float bcol = bias[col];
#pragma unroll
      for (int i = 0; i < 4; i++) {
        int row = bm0 + wm * 32 + fm * 16 + lhi * 4 + i;
        if (row < N) {
          float v = acc[fm][fn][i] + bcol;
          if (RELU_BF16_OUT) {
            ((unsigned short*)Cout)[(size_t)row * BN + col] = f2bf(fmaxf(v, 0.f));
          } else {
            ((float*)Cout)[(size_t)row * BN + col] = v;
          }
        }
      }
    }
  }
}

// ---------------- launch ----------------

extern "C" void kernel_launch(void* const* d_in, const int* in_sizes, int n_in,
                              void* d_out, int out_size, void* d_ws, size_t ws_size,
                              hipStream_t stream) {
  const float* x     = (const float*)d_in[0];
  const int*   eidx  = (const int*)d_in[1];
  const int*   et    = (const int*)d_in[2];
  const float* W1    = (const float*)d_in[3];
  const float* root1 = (const float*)d_in[4];
  const float* b1    = (const float*)d_in[5];
  const float* W2    = (const float*)d_in[6];
  const float* root2 = (const float*)d_in[7];
  const float* b2    = (const float*)d_in[8];
  float* out = (float*)d_out;

  const int IN = 128;
  const int N = in_sizes[0] / IN;
  const int E = in_sizes[2];
  const int* src = eidx;
  const int* dst = eidx + E;

  auto align = [](size_t v) { return (v + 255) & ~(size_t)255; };
  char* base = (char*)d_ws;
  size_t o = 0;
  float* deg = (float*)(base + o);
  o = align(o + (size_t)N * NRELS * 4);
  int* cnt = (int*)(base + o);
  size_t zero_end = o + (size_t)N * 4;  // memset covers deg..cnt
  o = align(zero_end);
  int* row_off = (int*)(base + o);
  o = align(o + (size_t)(N + 1) * 4);
  int* cursor = (int*)(base + o);
  o = align(o + (size_t)N * 4);
  int* epack = (int*)(base + o);
  o = align(o + (size_t)E * 4);
  unsigned short* xb = (unsigned short*)(base + o);       // [N][128] bf16
  o = align(o + (size_t)N * 128 * 2);
  unsigned short* hrelu = (unsigned short*)(base + o);    // [N][128] bf16
  o = align(o + (size_t)N * 128 * 2);
  unsigned short* Wt1 = (unsigned short*)(base + o);      // [128][1152]
  o = align(o + (size_t)128 * 1152 * 2);
  unsigned short* Wt2 = (unsigned short*)(base + o);      // [64][1152]
  o = align(o + (size_t)64 * 1152 * 2);
  unsigned short* Abig = (unsigned short*)(base + o);     // [N][1152] bf16

  hipMemsetAsync(deg, 0, zero_end, stream);

  const int tb = 256;
  deg_kernel<<<(E + tb - 1) / tb, tb, 0, stream>>>(dst, et, E, deg, cnt);
  scan_kernel<<<1, 1024, 0, stream>>>(cnt, N, row_off, cursor);
  bucket_kernel<<<(E + tb - 1) / tb, tb, 0, stream>>>(src, dst, et, E, cursor, epack);
  cvt_x_kernel<<<(N * 128 / 4 + tb - 1) / tb, tb, 0, stream>>>(x, xb, N * 128 / 4);
  cvt_w_kernel<<<(128 * 1152 + 64 * 1152 + tb - 1) / tb, tb, 0, stream>>>(
      W1, root1, W2, root2, Wt1, Wt2);

  const int agrid = (N + 3) / 4;
  const int gblocks = (N + 63) / 64;

  // layer 1: Abig = [agg(x), x] ; hrelu = bf16(relu(Abig @ Wt1^T + b1))
  agg_kernel<<<agrid, 256, 0, stream>>>(xb, deg, row_off, epack, Abig, N);
  gemm_mfma<128, true><<<gblocks, 256, 0, stream>>>(Abig, Wt1, b1, hrelu, N);

  // layer 2: Abig = [agg(hrelu), hrelu] ; out = Abig @ Wt2^T + b2 (fp32)
  agg_kernel<<<agrid, 256, 0, stream>>>(hrelu, deg, row_off, epack, Abig, N);
  gemm_mfma<64, false><<<gblocks, 256, 0, stream>>>(Abig, Wt2, b2, out, N);
}

// Round 5
// 297.591 us; speedup vs baseline: 6.9763x; 1.4119x over previous
//
#include <hip/hip_runtime.h>

#define NRELS 8

typedef __attribute__((ext_vector_type(8))) short short8;
typedef __attribute__((ext_vector_type(4))) float f32x4;

__device__ __forceinline__ unsigned short f2bf(float f) {
  unsigned int u = __float_as_uint(f);
  u += 0x7FFFu + ((u >> 16) & 1u);
  return (unsigned short)(u >> 16);
}
__device__ __forceinline__ float bf2f(unsigned short h) {
  return __uint_as_float(((unsigned int)h) << 16);
}

__device__ __forceinline__ void gload_lds16(const void* g, void* l) {
  __builtin_amdgcn_global_load_lds(
      (const __attribute__((address_space(1))) unsigned int*)g,
      (__attribute__((address_space(3))) unsigned int*)l, 16, 0, 0);
}

// ---------------- degree histogram (per (dst,rel)) ----------------

__global__ __launch_bounds__(256) void deg_kernel(
    const int* __restrict__ dstp, const int* __restrict__ et, int E,
    float* __restrict__ deg) {
  int i = blockIdx.x * blockDim.x + threadIdx.x;
  if (i < E) {
    atomicAdd(&deg[(size_t)dstp[i] * NRELS + et[i]], 1.0f);
  }
}

// ---------------- hierarchical exclusive scan over per-node degree ----------------
// phase 1: per-256-chunk local exclusive scan (count derived from deg rows) + block sum

__global__ __launch_bounds__(256) void scan1_kernel(
    const float* __restrict__ deg, int N, int* __restrict__ row_off,
    int* __restrict__ bsum) {
  __shared__ int s[256];
  int t = threadIdx.x;
  int i = blockIdx.x * 256 + t;
  int v = 0;
  if (i < N) {
    float c = 0.f;
#pragma unroll
    for (int r = 0; r < NRELS; r++) c += deg[(size_t)i * NRELS + r];
    v = (int)c;
  }
  s[t] = v;
  __syncthreads();
  for (int off = 1; off < 256; off <<= 1) {
    int u = (t >= off) ? s[t - off] : 0;
    __syncthreads();
    s[t] += u;
    __syncthreads();
  }
  if (i < N) row_off[i] = s[t] - v;  // local exclusive
  if (t == 255) bsum[blockIdx.x] = s[255];
}

// phase 2: single block exclusive-scans the block sums; bsum[NB] = grand total

__global__ __launch_bounds__(256) void scan2_kernel(int* __restrict__ bsum, int NB) {
  __shared__ int s[256];
  int t = threadIdx.x;
  int C = (NB + 255) / 256;
  int b0 = t * C, b1 = min(NB, b0 + C);
  int sum = 0;
  for (int i = b0; i < b1; i++) sum += bsum[i];
  s[t] = sum;
  __syncthreads();
  for (int off = 1; off < 256; off <<= 1) {
    int u = (t >= off) ? s[t - off] : 0;
    __syncthreads();
    s[t] += u;
    __syncthreads();
  }
  int base = (t == 0) ? 0 : s[t - 1];
  for (int i = b0; i < b1; i++) {
    int v = bsum[i];
    bsum[i] = base;
    base += v;
  }
  if (t == 255) bsum[NB] = s[255];
}

// phase 3: add block base, emit cursor; row_off[N] = total

__global__ __launch_bounds__(256) void scan3_kernel(
    int* __restrict__ row_off, int* __restrict__ cursor,
    const int* __restrict__ bsum, int N, int NB) {
  int i = blockIdx.x * 256 + threadIdx.x;
  if (i < N) {
    int v = row_off[i] + bsum[i >> 8];
    row_off[i] = v;
    cursor[i] = v;
  } else if (i == N) {
    row_off[N] = bsum[NB];
  }
}

// ---------------- bucket edges by dst; pack (src | et<<20) ----------------

__global__ __launch_bounds__(256) void bucket_kernel(
    const int* __restrict__ src, const int* __restrict__ dstp,
    const int* __restrict__ et, int E, int* __restrict__ cursor,
    int* __restrict__ epack) {
  int i = blockIdx.x * blockDim.x + threadIdx.x;
  if (i < E) {
    int pos = atomicAdd(&cursor[dstp[i]], 1);
    epack[pos] = src[i] | (et[i] << 20);
  }
}

// ---------------- fp32 -> bf16 feature conversion ----------------

__global__ __launch_bounds__(256) void cvt_x_kernel(
    const float* __restrict__ x, unsigned short* __restrict__ xb, int n4) {
  int i = blockIdx.x * blockDim.x + threadIdx.x;
  if (i < n4) {
    float4 v = ((const float4*)x)[i];
    ushort4 o;
    o.x = f2bf(v.x); o.y = f2bf(v.y); o.z = f2bf(v.z); o.w = f2bf(v.w);
    ((ushort4*)xb)[i] = o;
  }
}

// ---------------- weights -> bf16, transposed to [n][k] with k = [8*128 | 128] ------

__global__ __launch_bounds__(256) void cvt_w_kernel(
    const float* __restrict__ W1, const float* __restrict__ root1,
    const float* __restrict__ W2, const float* __restrict__ root2,
    unsigned short* __restrict__ Wt1, unsigned short* __restrict__ Wt2) {
  int idx = blockIdx.x * blockDim.x + threadIdx.x;
  const int T1 = 128 * 1152;
  const int T2 = 64 * 1152;
  if (idx < T1) {
    int n = idx / 1152, k = idx % 1152;
    float v = (k < 1024) ? W1[(size_t)k * 128 + n] : root1[(size_t)(k - 1024) * 128 + n];
    Wt1[idx] = f2bf(v);
  } else if (idx < T1 + T2) {
    int j = idx - T1;
    int n = j / 1152, k = j % 1152;
    float v = (k < 1024) ? W2[(size_t)k * 64 + n] : root2[(size_t)(k - 1024) * 64 + n];
    Wt2[j] = f2bf(v);
  }
}

// ---------------- aggregate all 8 relations + copy own row: Abig[node][1152] bf16 ----
// one wave per dst node; zero atomics; fp32 accumulation

__global__ __launch_bounds__(256) void agg_kernel(
    const unsigned short* __restrict__ feat,  // [N][128] bf16
    const float* __restrict__ deg,
    const int* __restrict__ row_off, const int* __restrict__ epack,
    unsigned short* __restrict__ Abig,        // [N][1152] bf16
    int N) {
  int wid = (int)((blockIdx.x * blockDim.x + threadIdx.x) >> 6);
  if (wid >= N) return;
  int lane = threadIdx.x & 63;
  float acc[NRELS][2];
#pragma unroll
  for (int r = 0; r < NRELS; r++) { acc[r][0] = 0.f; acc[r][1] = 0.f; }
  int b = row_off[wid], e = row_off[wid + 1];
  for (int i = b; i < e; i++) {
    int p = epack[i];
    int s = p & 0xFFFFF;
    int t = p >> 20;
    unsigned int pv = *(const unsigned int*)(feat + (size_t)s * 128 + lane * 2);
    float v0 = bf2f((unsigned short)(pv & 0xFFFF));
    float v1 = bf2f((unsigned short)(pv >> 16));
#pragma unroll
    for (int r = 0; r < NRELS; r++) {
      if (t == r) { acc[r][0] += v0; acc[r][1] += v1; }
    }
  }
  size_t arow = (size_t)wid * 1152;
#pragma unroll
  for (int r = 0; r < NRELS; r++) {
    float nrm = 1.0f / fmaxf(deg[(size_t)wid * NRELS + r], 1.0f);
    unsigned int o = (unsigned int)f2bf(acc[r][0] * nrm) |
                     ((unsigned int)f2bf(acc[r][1] * nrm) << 16);
    *(unsigned int*)(Abig + arow + r * 128 + lane * 2) = o;
  }
  unsigned int own = *(const unsigned int*)(feat + (size_t)wid * 128 + lane * 2);
  *(unsigned int*)(Abig + arow + 1024 + lane * 2) = own;
}

// ---------------- MFMA GEMM: C[N,BN] = A[N,1152] @ Bt[BN,1152]^T + bias ----------------

template <int BN, bool RELU_BF16_OUT>
__global__ __launch_bounds__(256) void gemm_mfma(
    const unsigned short* __restrict__ A,   // [N][1152] bf16
    const unsigned short* __restrict__ Bt,  // [BN][1152] bf16
    const float* __restrict__ bias,         // [BN] fp32
    void* __restrict__ Cout, int N) {
  constexpr int K = 1152;
  constexpr int BM = 64;
  constexpr int FM = 2;
  constexpr int FN = BN / 32;  // 4 (BN=128) or 2 (BN=64)

  __shared__ unsigned short As[BM * 64];  // 8 KB,  row stride 128 B
  __shared__ unsigned short Bs[BN * 64];  // 16/8 KB

  const int tid = threadIdx.x;
  const int lane = tid & 63;
  const int wid = tid >> 6;
  const int wm = wid >> 1, wn = wid & 1;
  const int l15 = lane & 15, lhi = lane >> 4;
  const int bm0 = blockIdx.x * BM;

  f32x4 acc[FM][FN];
#pragma unroll
  for (int i = 0; i < FM; i++)
#pragma unroll
    for (int j = 0; j < FN; j++) acc[i][j] = (f32x4){0.f, 0.f, 0.f, 0.f};

  int a_addr[2][FM], b_addr[2][FN];
#pragma unroll
  for (int fm = 0; fm < FM; fm++) {
    int row = wm * 32 + fm * 16 + l15;
#pragma unroll
    for (int ks = 0; ks < 2; ks++) {
      int colb = ks * 64 + lhi * 16;
      a_addr[ks][fm] = row * 128 + (colb ^ ((row & 7) << 4));
    }
  }
#pragma unroll
  for (int fn = 0; fn < FN; fn++) {
    int n = wn * (BN / 2) + fn * 16 + l15;
#pragma unroll
    for (int ks = 0; ks < 2; ks++) {
      int colb = ks * 64 + lhi * 16;
      b_addr[ks][fn] = n * 128 + (colb ^ ((n & 7) << 4));
    }
  }

  for (int kb = 0; kb < K; kb += 64) {
    if (kb) __syncthreads();
#pragma unroll
    for (int itr = 0; itr < BM / 32; itr++) {
      int o = itr * 4096 + wid * 1024 + lane * 16;
      int row = o >> 7;
      int scol = ((o & 127) ^ ((row & 7) << 4)) >> 1;
      int gr = bm0 + row;
      gr = gr < N ? gr : N - 1;
      gload_lds16(A + (size_t)gr * K + kb + scol,
                  (char*)As + itr * 4096 + wid * 1024);
    }
#pragma unroll
    for (int itr = 0; itr < BN / 32; itr++) {
      int o = itr * 4096 + wid * 1024 + lane * 16;
      int n = o >> 7;
      int scol = ((o & 127) ^ ((n & 7) << 4)) >> 1;
      gload_lds16(Bt + (size_t)n * K + kb + scol,
                  (char*)Bs + itr * 4096 + wid * 1024);
    }
    asm volatile("s_waitcnt vmcnt(0)" ::: "memory");
    __syncthreads();

#pragma unroll
    for (int ks = 0; ks < 2; ks++) {
      short8 af[FM], bf[FN];
#pragma unroll
      for (int fm = 0; fm < FM; fm++)
        af[fm] = *(const short8*)((const char*)As + a_addr[ks][fm]);
#pragma unroll
      for (int fn = 0; fn < FN; fn++)
        bf[fn] = *(const short8*)((const char*)Bs + b_addr[ks][fn]);
#pragma unroll
      for (int fm = 0; fm < FM; fm++)
#pragma unroll
        for (int fn = 0; fn < FN; fn++)
          acc[fm][fn] = __builtin_amdgcn_mfma_f32_16x16x32_bf16(
              af[fm], bf[fn], acc[fm][fn], 0, 0, 0);
    }
  }

#pragma unroll
  for (int fm = 0; fm < FM; fm++) {
#pragma unroll
    for (int fn = 0; fn < FN; fn++) {
      int col = wn * (BN / 2) + fn * 16 + l15;
      float bcol = bias[col];
#pragma unroll
      for (int i = 0; i < 4; i++) {
        int row = bm0 + wm * 32 + fm * 16 + lhi * 4 + i;
        if (row < N) {
          float v = acc[fm][fn][i] + bcol;
          if (RELU_BF16_OUT) {
            ((unsigned short*)Cout)[(size_t)row * BN + col] = f2bf(fmaxf(v, 0.f));
          } else {
            ((float*)Cout)[(size_t)row * BN + col] = v;
          }
        }
      }
    }
  }
}

// ---------------- launch ----------------

extern "C" void kernel_launch(void* const* d_in, const int* in_sizes, int n_in,
                              void* d_out, int out_size, void* d_ws, size_t ws_size,
                              hipStream_t stream) {
  const float* x     = (const float*)d_in[0];
  const int*   eidx  = (const int*)d_in[1];
  const int*   et    = (const int*)d_in[2];
  const float* W1    = (const float*)d_in[3];
  const float* root1 = (const float*)d_in[4];
  const float* b1    = (const float*)d_in[5];
  const float* W2    = (const float*)d_in[6];
  const float* root2 = (const float*)d_in[7];
  const float* b2    = (const float*)d_in[8];
  float* out = (float*)d_out;

  const int IN = 128;
  const int N = in_sizes[0] / IN;
  const int E = in_sizes[2];
  const int* src = eidx;
  const int* dst = eidx + E;
  const int NB = (N + 255) / 256;

  auto align = [](size_t v) { return (v + 255) & ~(size_t)255; };
  char* base = (char*)d_ws;
  size_t o = 0;
  float* deg = (float*)(base + o);
  size_t zero_end = (size_t)N * NRELS * 4;  // memset covers deg only
  o = align(zero_end);
  int* row_off = (int*)(base + o);
  o = align(o + (size_t)(N + 1) * 4);
  int* cursor = (int*)(base + o);
  o = align(o + (size_t)N * 4);
  int* bsum = (int*)(base + o);
  o = align(o + (size_t)(NB + 1) * 4);
  int* epack = (int*)(base + o);
  o = align(o + (size_t)E * 4);
  unsigned short* xb = (unsigned short*)(base + o);       // [N][128] bf16
  o = align(o + (size_t)N * 128 * 2);
  unsigned short* hrelu = (unsigned short*)(base + o);    // [N][128] bf16
  o = align(o + (size_t)N * 128 * 2);
  unsigned short* Wt1 = (unsigned short*)(base + o);      // [128][1152]
  o = align(o + (size_t)128 * 1152 * 2);
  unsigned short* Wt2 = (unsigned short*)(base + o);      // [64][1152]
  o = align(o + (size_t)64 * 1152 * 2);
  unsigned short* Abig = (unsigned short*)(base + o);     // [N][1152] bf16

  hipMemsetAsync(deg, 0, zero_end, stream);

  const int tb = 256;
  deg_kernel<<<(E + tb - 1) / tb, tb, 0, stream>>>(dst, et, E, deg);
  scan1_kernel<<<NB, 256, 0, stream>>>(deg, N, row_off, bsum);
  scan2_kernel<<<1, 256, 0, stream>>>(bsum, NB);
  scan3_kernel<<<(N + 256) / 256, 256, 0, stream>>>(row_off, cursor, bsum, N, NB);
  bucket_kernel<<<(E + tb - 1) / tb, tb, 0, stream>>>(src, dst, et, E, cursor, epack);
  cvt_x_kernel<<<(N * 128 / 4 + tb - 1) / tb, tb, 0, stream>>>(x, xb, N * 128 / 4);
  cvt_w_kernel<<<(128 * 1152 + 64 * 1152 + tb - 1) / tb, tb, 0, stream>>>(
      W1, root1, W2, root2, Wt1, Wt2);

  const int agrid = (N + 3) / 4;
  const int gblocks = (N + 63) / 64;

  // layer 1: Abig = [agg(x), x] ; hrelu = bf16(relu(Abig @ Wt1^T + b1))
  agg_kernel<<<agrid, 256, 0, stream>>>(xb, deg, row_off, epack, Abig, N);
  gemm_mfma<128, true><<<gblocks, 256, 0, stream>>>(Abig, Wt1, b1, hrelu, N);

  // layer 2: Abig = [agg(hrelu), hrelu] ; out = Abig @ Wt2^T + b2 (fp32)
  agg_kernel<<<agrid, 256, 0, stream>>>(hrelu, deg, row_off, epack, Abig, N);
  gemm_mfma<64, false><<<gblocks, 256, 0, stream>>>(Abig, Wt2, b2, out, N);
}

// Round 6
// 289.681 us; speedup vs baseline: 7.1667x; 1.0273x over previous
//
#include <hip/hip_runtime.h>

#define NRELS 8

typedef __attribute__((ext_vector_type(8))) short short8;
typedef __attribute__((ext_vector_type(4))) float f32x4;

__device__ __forceinline__ unsigned short f2bf(float f) {
  unsigned int u = __float_as_uint(f);
  u += 0x7FFFu + ((u >> 16) & 1u);
  return (unsigned short)(u >> 16);
}
__device__ __forceinline__ float bf2f(unsigned short h) {
  return __uint_as_float(((unsigned int)h) << 16);
}

__device__ __forceinline__ void gload_lds16(const void* g, void* l) {
  __builtin_amdgcn_global_load_lds(
      (const __attribute__((address_space(1))) unsigned int*)g,
      (__attribute__((address_space(3))) unsigned int*)l, 16, 0, 0);
}

// ---------------- histogram over (dst,rel) keys ----------------

__global__ __launch_bounds__(256) void hist_kernel(
    const int* __restrict__ dstp, const int* __restrict__ et, int E,
    int* __restrict__ hist) {
  int i = blockIdx.x * blockDim.x + threadIdx.x;
  if (i < E) {
    atomicAdd(&hist[(size_t)dstp[i] * NRELS + et[i]], 1);
  }
}

// ---------------- hierarchical exclusive scan over M = 8N keys ----------------

__global__ __launch_bounds__(256) void scan1_kernel(
    const int* __restrict__ hist, int M, int* __restrict__ row_off,
    int* __restrict__ bsum) {
  __shared__ int s[256];
  int t = threadIdx.x;
  int i = blockIdx.x * 256 + t;
  int v = (i < M) ? hist[i] : 0;
  s[t] = v;
  __syncthreads();
  for (int off = 1; off < 256; off <<= 1) {
    int u = (t >= off) ? s[t - off] : 0;
    __syncthreads();
    s[t] += u;
    __syncthreads();
  }
  if (i < M) row_off[i] = s[t] - v;  // local exclusive
  if (t == 255) bsum[blockIdx.x] = s[255];
}

__global__ __launch_bounds__(256) void scan2_kernel(int* __restrict__ bsum, int NB) {
  __shared__ int s[256];
  int t = threadIdx.x;
  int C = (NB + 255) / 256;
  int b0 = t * C, b1 = min(NB, b0 + C);
  int sum = 0;
  for (int i = b0; i < b1; i++) sum += bsum[i];
  s[t] = sum;
  __syncthreads();
  for (int off = 1; off < 256; off <<= 1) {
    int u = (t >= off) ? s[t - off] : 0;
    __syncthreads();
    s[t] += u;
    __syncthreads();
  }
  int base = (t == 0) ? 0 : s[t - 1];
  for (int i = b0; i < b1; i++) {
    int v = bsum[i];
    bsum[i] = base;
    base += v;
  }
  if (t == 255) bsum[NB] = s[255];
}

__global__ __launch_bounds__(256) void scan3_kernel(
    int* __restrict__ row_off, int* __restrict__ cursor,
    const int* __restrict__ bsum, int M, int NB) {
  int i = blockIdx.x * 256 + threadIdx.x;
  if (i < M) {
    int v = row_off[i] + bsum[i >> 8];
    row_off[i] = v;
    cursor[i] = v;
  } else if (i == M) {
    row_off[M] = bsum[NB];
  }
}

// ---------------- bucket edges by (dst,rel); store src ----------------

__global__ __launch_bounds__(256) void bucket_kernel(
    const int* __restrict__ src, const int* __restrict__ dstp,
    const int* __restrict__ et, int E, int* __restrict__ cursor,
    int* __restrict__ epack) {
  int i = blockIdx.x * blockDim.x + threadIdx.x;
  if (i < E) {
    int pos = atomicAdd(&cursor[(size_t)dstp[i] * NRELS + et[i]], 1);
    epack[pos] = src[i];
  }
}

// ---------------- fp32 -> bf16 feature conversion ----------------

__global__ __launch_bounds__(256) void cvt_x_kernel(
    const float* __restrict__ x, unsigned short* __restrict__ xb, int n4) {
  int i = blockIdx.x * blockDim.x + threadIdx.x;
  if (i < n4) {
    float4 v = ((const float4*)x)[i];
    ushort4 o;
    o.x = f2bf(v.x); o.y = f2bf(v.y); o.z = f2bf(v.z); o.w = f2bf(v.w);
    ((ushort4*)xb)[i] = o;
  }
}

// ---------------- weights -> bf16, transposed to [n][k] with k = [8*128 | 128] ------

__global__ __launch_bounds__(256) void cvt_w_kernel(
    const float* __restrict__ W1, const float* __restrict__ root1,
    const float* __restrict__ W2, const float* __restrict__ root2,
    unsigned short* __restrict__ Wt1, unsigned short* __restrict__ Wt2) {
  int idx = blockIdx.x * blockDim.x + threadIdx.x;
  const int T1 = 128 * 1152;
  const int T2 = 64 * 1152;
  if (idx < T1) {
    int n = idx / 1152, k = idx % 1152;
    float v = (k < 1024) ? W1[(size_t)k * 128 + n] : root1[(size_t)(k - 1024) * 128 + n];
    Wt1[idx] = f2bf(v);
  } else if (idx < T1 + T2) {
    int j = idx - T1;
    int n = j / 1152, k = j % 1152;
    float v = (k < 1024) ? W2[(size_t)k * 64 + n] : root2[(size_t)(k - 1024) * 64 + n];
    Wt2[j] = f2bf(v);
  }
}

// ---------------- aggregate: (dst,rel)-sorted segments, one accumulator ----------------
// one wave per dst node; per-relation segment sum; norm = 1/max(len,1)

__global__ __launch_bounds__(256) void agg_kernel(
    const unsigned short* __restrict__ feat,  // [N][128] bf16
    const int* __restrict__ row_off,          // [8N+1]
    const int* __restrict__ epack,            // [E] src ids
    unsigned short* __restrict__ Abig,        // [N][1152] bf16
    int N) {
  int wid = (int)((blockIdx.x * blockDim.x + threadIdx.x) >> 6);
  if (wid >= N) return;
  int lane = threadIdx.x & 63;
  int lo2 = lane * 2;
  size_t arow = (size_t)wid * 1152;
  int kbase = wid * NRELS;
  int b = row_off[kbase];
#pragma unroll
  for (int r = 0; r < NRELS; r++) {
    int e = row_off[kbase + r + 1];
    float a0 = 0.f, a1 = 0.f;
    for (int i = b; i < e; i++) {
      int s = epack[i];
      unsigned int pv = *(const unsigned int*)(feat + (size_t)s * 128 + lo2);
      a0 += bf2f((unsigned short)(pv & 0xFFFF));
      a1 += bf2f((unsigned short)(pv >> 16));
    }
    float nrm = 1.0f / (float)max(e - b, 1);
    unsigned int o = (unsigned int)f2bf(a0 * nrm) |
                     ((unsigned int)f2bf(a1 * nrm) << 16);
    *(unsigned int*)(Abig + arow + r * 128 + lo2) = o;
    b = e;
  }
  unsigned int own = *(const unsigned int*)(feat + (size_t)wid * 128 + lo2);
  *(unsigned int*)(Abig + arow + 1024 + lo2) = own;
}

// ---------------- MFMA GEMM: C[N,BN] = A[N,1152] @ Bt[BN,1152]^T + bias ----------------

template <int BN, bool RELU_BF16_OUT>
__global__ __launch_bounds__(256) void gemm_mfma(
    const unsigned short* __restrict__ A,   // [N][1152] bf16
    const unsigned short* __restrict__ Bt,  // [BN][1152] bf16
    const float* __restrict__ bias,         // [BN] fp32
    void* __restrict__ Cout, int N) {
  constexpr int K = 1152;
  constexpr int BM = 64;
  constexpr int FM = 2;
  constexpr int FN = BN / 32;  // 4 (BN=128) or 2 (BN=64)

  __shared__ unsigned short As[BM * 64];  // 8 KB,  row stride 128 B
  __shared__ unsigned short Bs[BN * 64];  // 16/8 KB

  const int tid = threadIdx.x;
  const int lane = tid & 63;
  const int wid = tid >> 6;
  const int wm = wid >> 1, wn = wid & 1;
  const int l15 = lane & 15, lhi = lane >> 4;
  const int bm0 = blockIdx.x * BM;

  f32x4 acc[FM][FN];
#pragma unroll
  for (int i = 0; i < FM; i++)
#pragma unroll
    for (int j = 0; j < FN; j++) acc[i][j] = (f32x4){0.f, 0.f, 0.f, 0.f};

  int a_addr[2][FM], b_addr[2][FN];
#pragma unroll
  for (int fm = 0; fm < FM; fm++) {
    int row = wm * 32 + fm * 16 + l15;
#pragma unroll
    for (int ks = 0; ks < 2; ks++) {
      int colb = ks * 64 + lhi * 16;
      a_addr[ks][fm] = row * 128 + (colb ^ ((row & 7) << 4));
    }
  }
#pragma unroll
  for (int fn = 0; fn < FN; fn++) {
    int n = wn * (BN / 2) + fn * 16 + l15;
#pragma unroll
    for (int ks = 0; ks < 2; ks++) {
      int colb = ks * 64 + lhi * 16;
      b_addr[ks][fn] = n * 128 + (colb ^ ((n & 7) << 4));
    }
  }

  for (int kb = 0; kb < K; kb += 64) {
    if (kb) __syncthreads();
#pragma unroll
    for (int itr = 0; itr < BM / 32; itr++) {
      int o = itr * 4096 + wid * 1024 + lane * 16;
      int row = o >> 7;
      int scol = ((o & 127) ^ ((row & 7) << 4)) >> 1;
      int gr = bm0 + row;
      gr = gr < N ? gr : N - 1;
      gload_lds16(A + (size_t)gr * K + kb + scol,
                  (char*)As + itr * 4096 + wid * 1024);
    }
#pragma unroll
    for (int itr = 0; itr < BN / 32; itr++) {
      int o = itr * 4096 + wid * 1024 + lane * 16;
      int n = o >> 7;
      int scol = ((o & 127) ^ ((n & 7) << 4)) >> 1;
      gload_lds16(Bt + (size_t)n * K + kb + scol,
                  (char*)Bs + itr * 4096 + wid * 1024);
    }
    asm volatile("s_waitcnt vmcnt(0)" ::: "memory");
    __syncthreads();

#pragma unroll
    for (int ks = 0; ks < 2; ks++) {
      short8 af[FM], bf[FN];
#pragma unroll
      for (int fm = 0; fm < FM; fm++)
        af[fm] = *(const short8*)((const char*)As + a_addr[ks][fm]);
#pragma unroll
      for (int fn = 0; fn < FN; fn++)
        bf[fn] = *(const short8*)((const char*)Bs + b_addr[ks][fn]);
#pragma unroll
      for (int fm = 0; fm < FM; fm++)
#pragma unroll
        for (int fn = 0; fn < FN; fn++)
          acc[fm][fn] = __builtin_amdgcn_mfma_f32_16x16x32_bf16(
              af[fm], bf[fn], acc[fm][fn], 0, 0, 0);
    }
  }

#pragma unroll
  for (int fm = 0; fm < FM; fm++) {
#pragma unroll
    for (int fn = 0; fn < FN; fn++) {
      int col = wn * (BN / 2) + fn * 16 + l15;
      float bcol = bias[col];
#pragma unroll
      for (int i = 0; i < 4; i++) {
        int row = bm0 + wm * 32 + fm * 16 + lhi * 4 + i;
        if (row < N) {
          float v = acc[fm][fn][i] + bcol;
          if (RELU_BF16_OUT) {
            ((unsigned short*)Cout)[(size_t)row * BN + col] = f2bf(fmaxf(v, 0.f));
          } else {
            ((float*)Cout)[(size_t)row * BN + col] = v;
          }
        }
      }
    }
  }
}

// ---------------- launch ----------------

extern "C" void kernel_launch(void* const* d_in, const int* in_sizes, int n_in,
                              void* d_out, int out_size, void* d_ws, size_t ws_size,
                              hipStream_t stream) {
  const float* x     = (const float*)d_in[0];
  const int*   eidx  = (const int*)d_in[1];
  const int*   et    = (const int*)d_in[2];
  const float* W1    = (const float*)d_in[3];
  const float* root1 = (const float*)d_in[4];
  const float* b1    = (const float*)d_in[5];
  const float* W2    = (const float*)d_in[6];
  const float* root2 = (const float*)d_in[7];
  const float* b2    = (const float*)d_in[8];
  float* out = (float*)d_out;

  const int IN = 128;
  const int N = in_sizes[0] / IN;
  const int E = in_sizes[2];
  const int* src = eidx;
  const int* dst = eidx + E;
  const int M = N * NRELS;            // (dst,rel) key space
  const int NB = (M + 255) / 256;

  auto align = [](size_t v) { return (v + 255) & ~(size_t)255; };
  char* base = (char*)d_ws;
  size_t o = 0;
  int* hist = (int*)(base + o);
  size_t zero_end = (size_t)M * 4;    // memset covers hist only
  o = align(zero_end);
  int* row_off = (int*)(base + o);
  o = align(o + (size_t)(M + 1) * 4);
  int* cursor = (int*)(base + o);
  o = align(o + (size_t)M * 4);
  int* bsum = (int*)(base + o);
  o = align(o + (size_t)(NB + 1) * 4);
  int* epack = (int*)(base + o);
  o = align(o + (size_t)E * 4);
  unsigned short* xb = (unsigned short*)(base + o);       // [N][128] bf16
  o = align(o + (size_t)N * 128 * 2);
  unsigned short* hrelu = (unsigned short*)(base + o);    // [N][128] bf16
  o = align(o + (size_t)N * 128 * 2);
  unsigned short* Wt1 = (unsigned short*)(base + o);      // [128][1152]
  o = align(o + (size_t)128 * 1152 * 2);
  unsigned short* Wt2 = (unsigned short*)(base + o);      // [64][1152]
  o = align(o + (size_t)64 * 1152 * 2);
  unsigned short* Abig = (unsigned short*)(base + o);     // [N][1152] bf16

  hipMemsetAsync(hist, 0, zero_end, stream);

  const int tb = 256;
  hist_kernel<<<(E + tb - 1) / tb, tb, 0, stream>>>(dst, et, E, hist);
  scan1_kernel<<<NB, 256, 0, stream>>>(hist, M, row_off, bsum);
  scan2_kernel<<<1, 256, 0, stream>>>(bsum, NB);
  scan3_kernel<<<(M + 256) / 256, 256, 0, stream>>>(row_off, cursor, bsum, M, NB);
  bucket_kernel<<<(E + tb - 1) / tb, tb, 0, stream>>>(src, dst, et, E, cursor, epack);
  cvt_x_kernel<<<(N * 128 / 4 + tb - 1) / tb, tb, 0, stream>>>(x, xb, N * 128 / 4);
  cvt_w_kernel<<<(128 * 1152 + 64 * 1152 + tb - 1) / tb, tb, 0, stream>>>(
      W1, root1, W2, root2, Wt1, Wt2);

  const int agrid = (N + 3) / 4;
  const int gblocks = (N + 63) / 64;

  // layer 1: Abig = [agg(x), x] ; hrelu = bf16(relu(Abig @ Wt1^T + b1))
  agg_kernel<<<agrid, 256, 0, stream>>>(xb, row_off, epack, Abig, N);
  gemm_mfma<128, true><<<gblocks, 256, 0, stream>>>(Abig, Wt1, b1, hrelu, N);

  // layer 2: Abig = [agg(hrelu), hrelu] ; out = Abig @ Wt2^T + b2 (fp32)
  agg_kernel<<<agrid, 256, 0, stream>>>(hrelu, row_off, epack, Abig, N);
  gemm_mfma<64, false><<<gblocks, 256, 0, stream>>>(Abig, Wt2, b2, out, N);
}